// Round 4
// baseline (332.569 us; speedup 1.0000x reference)
//
#include <hip/hip_runtime.h>
#include <cstdint>

#define NPX 2304      // 48*48
#define MM 6912       // 3*2304
#define NW 108        // MM/64
#define TOPK 2000
#define NEGV -1000000000.0f
#define OBJ_THRF 0.3f
#define IOU_THRF 0.7f
#define IMGF 768.0f
#define KSPLIT 4      // conv k-splits: 64 ic per split

typedef unsigned long long u64;
typedef unsigned int u32;

__device__ __forceinline__ u64 shfl64(u64 v, int src) {
  int lo = __shfl((int)(v & 0xffffffffull), src, 64);
  int hi = __shfl((int)(v >> 32), src, 64);
  return ((u64)(u32)hi << 32) | (u32)lo;
}

// ---------------- weight transpose: wt[(ic*9+tap)][oc] = cw[oc][ic*9+tap] ---
__global__ __launch_bounds__(256) void k_wt(const float* __restrict__ cw,
                                            float* __restrict__ wt) {
  __shared__ float t[64][65];
  const int it0 = blockIdx.x * 64;   // grid.x = 36 (2304/64)
  const int oc0 = blockIdx.y * 64;   // grid.y = 4
  const int tx = threadIdx.x & 63;
  const int ty = threadIdx.x >> 6;
#pragma unroll
  for (int k = 0; k < 16; ++k) {
    int oc = ty + k * 4;
    t[oc][tx] = cw[(oc0 + oc) * 2304 + it0 + tx];  // coalesced read
  }
  __syncthreads();
#pragma unroll
  for (int k = 0; k < 16; ++k) {
    int it = ty + k * 4;
    wt[(it0 + it) * 256 + oc0 + tx] = t[tx][it];   // coalesced write
  }
}

// ---------------- conv 3x3, 256->256, fp32, scalar-weight form ----------------
// grid (9 px-chunks, 16 oc-tiles, KSPLIT); block 256.
// thread: 1 px, 16 oc accs. Per (ic,tap): 1 LDS x-read + 16 FMA w/ SGPR weight.
__global__ __launch_bounds__(256) void k_conv(const float* __restrict__ x,
                                              const float* __restrict__ wt,
                                              float* __restrict__ part) {
  __shared__ float xs[16 * 8 * 52];  // 16 ic x 8 rows x 52 cols = 26,624 B
  const int tid = threadIdx.x;
  const int px = blockIdx.x * 256 + tid;
  const int oc0 = blockIdx.y * 16;
  const int ks = blockIdx.z;
  const int row = px / 48, col = px % 48;
  const int r0 = (blockIdx.x * 256) / 48;  // first row of this px-chunk
  const int rbase = row - r0;              // 0..5

  float acc[16];
#pragma unroll
  for (int k = 0; k < 16; ++k) acc[k] = 0.f;

  for (int icc = 0; icc < 64 / 16; ++icc) {
    const int ic0 = ks * 64 + icc * 16;
    // stage x: 16 ic x rows r0-1..r0+6 x cols -1..48 (zero halo)
    for (int e = tid; e < 16 * 8 * 50; e += 256) {
      int ic = e / 400, rem = e % 400;
      int r = rem / 50, c = rem % 50 - 1;
      int gr = r0 - 1 + r;
      float v = 0.f;
      if (c >= 0 && c < 48 && gr >= 0 && gr < 48)
        v = x[(ic0 + ic) * NPX + gr * 48 + c];
      xs[(ic * 8 + r) * 52 + (c + 1)] = v;
    }
    __syncthreads();
    for (int ic = 0; ic < 16; ++ic) {
      float xv[9];
#pragma unroll
      for (int dr = 0; dr < 3; ++dr)
#pragma unroll
        for (int dc = 0; dc < 3; ++dc)
          xv[dr * 3 + dc] = xs[(ic * 8 + rbase + dr) * 52 + col + dc];
      const float* wrow = wt + (size_t)(ic0 + ic) * 9 * 256 + oc0;
#pragma unroll
      for (int t = 0; t < 9; ++t) {
        const float* wp = wrow + t * 256;  // wave-uniform -> s_load_dwordx16
#pragma unroll
        for (int k = 0; k < 16; ++k) acc[k] += xv[t] * wp[k];
      }
    }
    __syncthreads();
  }
#pragma unroll
  for (int k = 0; k < 16; ++k)
    part[((size_t)ks * 256 + oc0 + k) * NPX + px] = acc[k];
}

// ---------------- heads + anchor decode (sums KSPLIT partials) --------------
__global__ __launch_bounds__(256) void k_decode(const float* __restrict__ part,
                                                const float* __restrict__ cb,
                                                const float* __restrict__ dw,
                                                const float* __restrict__ db,
                                                const float* __restrict__ rw,
                                                const float* __restrict__ rb,
                                                const float* __restrict__ anch,
                                                float* __restrict__ s,
                                                float4* __restrict__ boxes) {
  __shared__ float wl[256 * 16];
  const int tid = threadIdx.x;
  const int p = blockIdx.x * 256 + tid;
  for (int e = tid; e < 3840; e += 256) {
    int o = e % 15, c = e / 15;
    wl[c * 16 + o] = (o < 3) ? dw[o * 256 + c] : rw[(o - 3) * 256 + c];
  }
  __syncthreads();
  float acc[15];
#pragma unroll
  for (int o = 0; o < 15; o++) acc[o] = 0.f;
  for (int c = 0; c < 256; ++c) {
    float v = cb[c];
#pragma unroll
    for (int kks = 0; kks < KSPLIT; ++kks)
      v += part[((size_t)kks * 256 + c) * NPX + p];
#pragma unroll
    for (int o = 0; o < 15; o++) acc[o] += v * wl[c * 16 + o];
  }
  const float4* an4 = (const float4*)anch;
#pragma unroll
  for (int a = 0; a < 3; ++a) {
    int m = a * NPX + p;
    float logit = acc[a] + db[a];
    float score = 1.f / (1.f + expf(-logit));
    float dxv = acc[3 + 0 + a] + rb[0 + a];
    float dyv = acc[3 + 3 + a] + rb[3 + a];
    float dwv = acc[3 + 6 + a] + rb[6 + a];
    float dhv = acc[3 + 9 + a] + rb[9 + a];
    float4 an = an4[m];
    float aw = an.z - an.x;
    float ah = an.w - an.y;
    float acx = an.y + aw * 0.5f;  // NOTE: intentionally swapped (reference quirk)
    float acy = an.x + ah * 0.5f;  // NOTE: intentionally swapped (reference quirk)
    float pxc = acx + dxv * aw;
    float pyc = acy + dyv * ah;
    float pw = aw * expf(dwv);
    float ph = ah * expf(dhv);
    float b0 = pxc - pw * 0.5f, b1 = pyc - ph * 0.5f;
    float b2 = pxc + pw * 0.5f, b3 = pyc + ph * 0.5f;
    b0 = fminf(fmaxf(b0, 0.f), IMGF);
    b1 = fminf(fmaxf(b1, 0.f), IMGF);
    b2 = fminf(fmaxf(b2, 0.f), IMGF);
    b3 = fminf(fmaxf(b3, 0.f), IMGF);
    float hts = b2 - b0, wds = b3 - b1;
    bool valid = (hts > 0.f) && (wds > 0.f) && (score > OBJ_THRF);
    s[m] = valid ? score : NEGV;
    boxes[m] = make_float4(b0, b1, b2, b3);
  }
}

// ---------------- sort phase 1: 8 blocks x 1024-elem bitonic runs ----------
__global__ __launch_bounds__(256) void k_sortA(const float* __restrict__ s,
                                               u64* __restrict__ keys) {
  __shared__ u64 lds[1024];
  const int tid = threadIdx.x;
  const int b = blockIdx.x;
  for (int v = tid; v < 1024; v += 256) {
    int i = b * 1024 + v;
    u64 p;
    if (i < MM) {
      u32 u = __float_as_uint(s[i]);
      u = u ^ (u32)(((int)u >> 31) | 0x80000000);
      p = ((u64)(~u) << 32) | (u32)i;
    } else {
      p = ~0ull;
    }
    lds[v] = p;
  }
  for (u32 kk = 2; kk <= 1024; kk <<= 1) {
    for (u32 j = kk >> 1; j > 0; j >>= 1) {
      __syncthreads();
#pragma unroll 2
      for (int t = tid; t < 512; t += 256) {
        int i = ((t & ~(j - 1)) << 1) | (t & (j - 1));
        int l = i | j;
        bool up = ((i & kk) == 0);
        u64 a = lds[i], c = lds[l];
        u64 mn = a < c ? a : c;
        u64 mx = a < c ? c : a;
        lds[i] = up ? mn : mx;
        lds[l] = up ? mx : mn;
      }
    }
  }
  __syncthreads();
  for (int v = tid; v < 1024; v += 256) keys[b * 1024 + v] = lds[v];
}

// ---------------- sort phase 2: merge-path rounds ----------------
__global__ __launch_bounds__(256) void k_merge(const u64* __restrict__ in,
                                               u64* __restrict__ outk, int L, int fin,
                                               const float* __restrict__ s,
                                               const float4* __restrict__ boxes,
                                               float* __restrict__ ssc,
                                               float4* __restrict__ sboxes) {
  const int i = blockIdx.x * 256 + threadIdx.x;  // 0..8191
  const int pair = i / (2 * L);
  const int r = i - pair * 2 * L;
  const u64* A = in + (size_t)pair * 2 * L;
  const u64* B = A + L;
  int lo = (r > L) ? (r - L) : 0;
  int hi = (r < L) ? r : L;
  while (lo < hi) {
    int mid = (lo + hi) >> 1;
    if (A[mid] < B[r - 1 - mid]) lo = mid + 1; else hi = mid;
  }
  int a = lo, bi = r - lo;
  u64 av = (a < L) ? A[a] : ~0ull;
  u64 bv = (bi < L) ? B[bi] : ~0ull;
  u64 o = (av < bv) ? av : bv;
  outk[i] = o;
  if (fin && i < MM) {
    int idx = (int)(u32)o;
    ssc[i] = s[idx];
    sboxes[i] = boxes[idx];
  }
}

// ---------------- zero-init nz bitmaps ----------------
__global__ __launch_bounds__(256) void k_zero(u64* __restrict__ nz) {
  int i = blockIdx.x * 256 + threadIdx.x;
  if (i < MM * 2) nz[i] = 0;
}

// ---------------- IOU suppression bit-matrix (transposed) ----------------
__global__ __launch_bounds__(256) void k_mask(const float4* __restrict__ sboxes,
                                              u64* __restrict__ mask_t,
                                              u64* __restrict__ nz) {
  __shared__ float4 rb_[64];
  const int rt = blockIdx.x;
  const int w = blockIdx.y * 4 + (threadIdx.x >> 6);
  const int lane = threadIdx.x & 63;
  if (threadIdx.x < 64) rb_[threadIdx.x] = sboxes[rt * 64 + threadIdx.x];
  __syncthreads();
  if (w < rt) return;
  float4 c = sboxes[w * 64 + lane];
  float areaC = (c.z - c.x) * (c.w - c.y);
  u64 myw = 0;
  for (int r = 0; r < 64; ++r) {
    float4 b = rb_[r];
    float iw = fmaxf(fminf(b.z, c.z) - fmaxf(b.x, c.x), 0.f);
    float ih = fmaxf(fminf(b.w, c.w) - fmaxf(b.y, c.y), 0.f);
    float inter = iw * ih;
    float areaB = (b.z - b.x) * (b.w - b.y);
    float un = fmaxf(areaB + areaC - inter, 1e-9f);
    bool bit = (inter / un) > IOU_THRF;
    u64 bal = __ballot(bit);
    if (lane == r) myw = bal;
  }
  mask_t[(size_t)w * MM + rt * 64 + lane] = myw;
  if (myw) atomicOr(&nz[(rt * 64 + lane) * 2 + (w >> 6)], 1ull << (w & 63));
}

// ---------------- serial NMS scan + output ----------------
__global__ __launch_bounds__(256) void k_scan(const u64* __restrict__ mask_t,
                                              const u64* __restrict__ nz,
                                              const float* __restrict__ ssc,
                                              const float4* __restrict__ sboxes,
                                              float* __restrict__ out) {
  __shared__ u64 remv[NW];
  __shared__ u64 keepw[NW];
  __shared__ int blist[64];
  __shared__ int nkS;
  __shared__ int kcntS;
  __shared__ int pref[NW];
  const int tid = threadIdx.x;
  if (tid < NW) { remv[tid] = 0; keepw[tid] = 0; }
  if (tid == 0) kcntS = 0;
  __syncthreads();

  for (int c = 0; c < NW; ++c) {
    if (tid < 64) {
      const int lane = tid;
      u64 dg = mask_t[(size_t)c * MM + c * 64 + lane];
      float sv = ssc[c * 64 + lane];
      u64 vb = __ballot(sv > OBJ_THRF);
      u64 w0 = remv[c];
      u64 cand = vb & ~w0;
      u64 above = (lane < 63) ? ~((2ull << lane) - 1ull) : 0ull;
      bool inC = ((cand >> lane) & 1ull) != 0;
      u64 conf = __ballot(inC && ((dg & above & cand) != 0ull));
      u64 kb;
      if (conf == 0ull) {
        kb = cand;
      } else {
        u64 w = w0;
        kb = 0;
        u64 rem = cand;
        while (rem) {
          int b = __ffsll(rem) - 1;
          kb |= (1ull << b);
          w |= shfl64(dg, b);
          rem = vb & ~w;
        }
      }
      int below = __popcll(kb & ((1ull << lane) - 1ull));
      if ((kb >> lane) & 1ull) blist[below] = lane;
      if (lane == 0) {
        keepw[c] = kb;
        nkS = __popcll(kb);
        kcntS += __popcll(kb);
      }
    }
    __syncthreads();
    int nk = nkS;
    if (tid < nk) {
      int row = c * 64 + blist[tid];
      u64 nz0 = nz[row * 2], nz1 = nz[row * 2 + 1];
      if (c < 64) {
        nz0 &= (c < 63) ? ~((2ull << c) - 1ull) : 0ull;
      } else {
        nz0 = 0;
        int cc = c - 64;
        nz1 &= ~((2ull << cc) - 1ull);
      }
      while (nz0) {
        int wv = __ffsll(nz0) - 1; nz0 &= nz0 - 1;
        atomicOr(&remv[wv], mask_t[(size_t)wv * MM + row]);
      }
      while (nz1) {
        int wv = __ffsll(nz1) - 1; nz1 &= nz1 - 1;
        atomicOr(&remv[wv + 64], mask_t[(size_t)(wv + 64) * MM + row]);
      }
    }
    __syncthreads();
    if (kcntS >= TOPK) break;
  }

  if (tid == 0) {
    int run = 0;
    for (int cc = 0; cc < NW; ++cc) { pref[cc] = run; run += __popcll(keepw[cc]); }
  }
  __syncthreads();
  for (int e = tid; e < TOPK * 5; e += 256) out[e] = (e < TOPK) ? -1.0f : 0.0f;
  __syncthreads();
  float4* ob = (float4*)(out + TOPK);
  for (int i = tid; i < MM; i += 256) {
    int cc = i >> 6, b = i & 63;
    u64 kb = keepw[cc];
    if ((kb >> b) & 1ull) {
      int rank = pref[cc] + __popcll(kb & ((1ull << b) - 1ull));
      if (rank < TOPK) {
        out[rank] = ssc[i];
        ob[rank] = sboxes[i];
      }
    }
  }
}

extern "C" void kernel_launch(void* const* d_in, const int* in_sizes, int n_in,
                              void* d_out, int out_size, void* d_ws, size_t ws_size,
                              hipStream_t stream) {
  const float* x  = (const float*)d_in[0];
  const float* cw = (const float*)d_in[1];
  const float* cb = (const float*)d_in[2];
  const float* dw = (const float*)d_in[3];
  const float* db = (const float*)d_in[4];
  const float* rw = (const float*)d_in[5];
  const float* rb = (const float*)d_in[6];
  const float* an = (const float*)d_in[7];
  char* ws = (char*)d_ws;
  // Time-phased aliasing:
  //   phase 1 (k_wt,k_conv,k_decode): part [0..9.44MB), wt [9.44..11.80MB)
  //   phase 2 (k_zero..k_merge): keysA/B at [0..128KB), nz at 5,971,968 (part dead)
  //   phase 3 (k_mask,k_scan): mask at [0..5,971,968) (keys dead after final merge)
  float*  part   = (float*)(ws);                 // 9,437,184 B
  u64*    keysA  = (u64*)(ws);                   // 65,536 B
  u64*    keysB  = (u64*)(ws + 65536);           // 65,536 B
  u64*    mask   = (u64*)(ws);                   // 5,971,968 B
  u64*    nz     = (u64*)(ws + 5971968);         // 110,592 B
  float*  wt     = (float*)(ws + 9437184);       // 2,359,296 B
  float*  s      = (float*)(ws + 11796480);      // 27,648 B
  float4* boxes  = (float4*)(ws + 11824128);     // 110,592 B
  float*  ssc    = (float*)(ws + 11934720);      // 27,648 B
  float4* sboxes = (float4*)(ws + 11962368);     // 110,592 B -> total 12,072,960 B
  float* out = (float*)d_out;

  hipLaunchKernelGGL(k_wt, dim3(36, 4), dim3(256), 0, stream, cw, wt);
  hipLaunchKernelGGL(k_conv, dim3(9, 16, KSPLIT), dim3(256), 0, stream, x, wt, part);
  hipLaunchKernelGGL(k_decode, dim3(9), dim3(256), 0, stream, part, cb, dw, db, rw, rb, an, s, boxes);
  hipLaunchKernelGGL(k_zero, dim3(54), dim3(256), 0, stream, nz);
  hipLaunchKernelGGL(k_sortA, dim3(8), dim3(256), 0, stream, s, keysA);
  hipLaunchKernelGGL(k_merge, dim3(32), dim3(256), 0, stream, keysA, keysB, 1024, 0, s, boxes, ssc, sboxes);
  hipLaunchKernelGGL(k_merge, dim3(32), dim3(256), 0, stream, keysB, keysA, 2048, 0, s, boxes, ssc, sboxes);
  hipLaunchKernelGGL(k_merge, dim3(32), dim3(256), 0, stream, keysA, keysB, 4096, 1, s, boxes, ssc, sboxes);
  hipLaunchKernelGGL(k_mask, dim3(108, 27), dim3(256), 0, stream, sboxes, mask, nz);
  hipLaunchKernelGGL(k_scan, dim3(1), dim3(256), 0, stream, mask, nz, ssc, sboxes, out);
}

// Round 5
// 267.465 us; speedup vs baseline: 1.2434x; 1.2434x over previous
//
#include <hip/hip_runtime.h>
#include <cstdint>

#define NPX 2304      // 48*48
#define MM 6912       // 3*2304
#define NW 108        // MM/64
#define TOPK 2000
#define NEGV -1000000000.0f
#define OBJ_THRF 0.3f
#define IOU_THRF 0.7f
#define IMGF 768.0f
#define KSPLIT 8      // conv k-splits: 32 ic per split

typedef unsigned long long u64;
typedef unsigned int u32;

__device__ __forceinline__ u64 shfl64(u64 v, int src) {
  int lo = __shfl((int)(v & 0xffffffffull), src, 64);
  int hi = __shfl((int)(v >> 32), src, 64);
  return ((u64)(u32)hi << 32) | (u32)lo;
}

// ---------------- weight transpose: wt[(ic*9+tap)][oc] = cw[oc][ic*9+tap] ---
__global__ __launch_bounds__(256) void k_wt(const float* __restrict__ cw,
                                            float* __restrict__ wt) {
  __shared__ float t[64][65];
  const int it0 = blockIdx.x * 64;   // grid.x = 36 (2304/64)
  const int oc0 = blockIdx.y * 64;   // grid.y = 4
  const int tx = threadIdx.x & 63;
  const int ty = threadIdx.x >> 6;
#pragma unroll
  for (int k = 0; k < 16; ++k) {
    int oc = ty + k * 4;
    t[oc][tx] = cw[(oc0 + oc) * 2304 + it0 + tx];  // coalesced read
  }
  __syncthreads();
#pragma unroll
  for (int k = 0; k < 16; ++k) {
    int it = ty + k * 4;
    wt[(it0 + it) * 256 + oc0 + tx] = t[tx][it];   // coalesced write
  }
}

// ---------------- conv 3x3, 256->256, fp32, scalar-weight form ----------------
// grid (9 px-chunks, 16 oc-tiles, 8 k-splits) = 1152 blocks (18 waves/CU).
// thread: 1 px, 16 oc accs. Per (ic,tap): 1 LDS x-read + 16 FMA w/ SGPR weight.
__global__ __launch_bounds__(256) void k_conv(const float* __restrict__ x,
                                              const float* __restrict__ wt,
                                              float* __restrict__ part) {
  __shared__ float xs[16 * 8 * 52];  // 16 ic x 8 rows x 52 cols = 26,624 B
  const int tid = threadIdx.x;
  const int px = blockIdx.x * 256 + tid;
  const int oc0 = blockIdx.y * 16;
  const int ks = blockIdx.z;
  const int row = px / 48, col = px % 48;
  const int r0 = (blockIdx.x * 256) / 48;  // first row of this px-chunk
  const int rbase = row - r0;              // 0..5

  float acc[16];
#pragma unroll
  for (int k = 0; k < 16; ++k) acc[k] = 0.f;

  for (int icc = 0; icc < 2; ++icc) {
    const int ic0 = ks * 32 + icc * 16;
    // stage x: 16 ic x rows r0-1..r0+6 x cols -1..48 (zero halo)
    for (int e = tid; e < 16 * 8 * 50; e += 256) {
      int ic = e / 400, rem = e % 400;
      int r = rem / 50, c = rem % 50 - 1;
      int gr = r0 - 1 + r;
      float v = 0.f;
      if (c >= 0 && c < 48 && gr >= 0 && gr < 48)
        v = x[(ic0 + ic) * NPX + gr * 48 + c];
      xs[(ic * 8 + r) * 52 + (c + 1)] = v;
    }
    __syncthreads();
    for (int ic = 0; ic < 16; ++ic) {
      float xv[9];
#pragma unroll
      for (int dr = 0; dr < 3; ++dr)
#pragma unroll
        for (int dc = 0; dc < 3; ++dc)
          xv[dr * 3 + dc] = xs[(ic * 8 + rbase + dr) * 52 + col + dc];
      const float* wrow = wt + (size_t)(ic0 + ic) * 9 * 256 + oc0;
#pragma unroll
      for (int t = 0; t < 9; ++t) {
        const float* wp = wrow + t * 256;  // wave-uniform -> s_load_dwordx16
#pragma unroll
        for (int k = 0; k < 16; ++k) acc[k] += xv[t] * wp[k];
      }
    }
    __syncthreads();
  }
#pragma unroll
  for (int k = 0; k < 16; ++k)
    part[((size_t)ks * 256 + oc0 + k) * NPX + px] = acc[k];
}

// ---------------- heads + anchor decode (parallel: 36 blocks, c-split x4) ---
// thread t: px = blk*64 + (t&63), c-quarter = t>>6 (wave-uniform). LDS reduce.
__global__ __launch_bounds__(256) void k_decode(const float* __restrict__ part,
                                                const float* __restrict__ cb,
                                                const float* __restrict__ dw,
                                                const float* __restrict__ db,
                                                const float* __restrict__ rw,
                                                const float* __restrict__ rb,
                                                const float* __restrict__ anch,
                                                float* __restrict__ s,
                                                float4* __restrict__ boxes) {
  __shared__ float wl[256 * 16];        // 16 KB  [c][o]
  __shared__ float red[4 * 64 * 17];    // 17 KB  [cq][pxl][o], stride 17
  const int tid = threadIdx.x;
  const int pxl = tid & 63;
  const int cq = tid >> 6;              // wave-uniform
  const int px = blockIdx.x * 64 + pxl;
  for (int e = tid; e < 3840; e += 256) {
    int o = e % 15, c = e / 15;
    wl[c * 16 + o] = (o < 3) ? dw[o * 256 + c] : rw[(o - 3) * 256 + c];
  }
  __syncthreads();
  float acc[15];
#pragma unroll
  for (int o = 0; o < 15; o++) acc[o] = 0.f;
  for (int ci = 0; ci < 64; ++ci) {
    int c = cq * 64 + ci;
    float v = cb[c];
#pragma unroll
    for (int kks = 0; kks < KSPLIT; ++kks)
      v += part[((size_t)kks * 256 + c) * NPX + px];
#pragma unroll
    for (int o = 0; o < 15; o++) acc[o] += v * wl[c * 16 + o];
  }
#pragma unroll
  for (int o = 0; o < 15; o++) red[(cq * 64 + pxl) * 17 + o] = acc[o];
  __syncthreads();
  if (tid < 64) {
    const int p = blockIdx.x * 64 + tid;
    float a[15];
#pragma unroll
    for (int o = 0; o < 15; o++)
      a[o] = red[tid * 17 + o] + red[(64 + tid) * 17 + o] +
             red[(128 + tid) * 17 + o] + red[(192 + tid) * 17 + o];
    const float4* an4 = (const float4*)anch;
#pragma unroll
    for (int aa = 0; aa < 3; ++aa) {
      int m = aa * NPX + p;
      float logit = a[aa] + db[aa];
      float score = 1.f / (1.f + expf(-logit));
      float dxv = a[3 + 0 + aa] + rb[0 + aa];
      float dyv = a[3 + 3 + aa] + rb[3 + aa];
      float dwv = a[3 + 6 + aa] + rb[6 + aa];
      float dhv = a[3 + 9 + aa] + rb[9 + aa];
      float4 an = an4[m];
      float aw = an.z - an.x;
      float ah = an.w - an.y;
      float acx = an.y + aw * 0.5f;  // NOTE: intentionally swapped (reference quirk)
      float acy = an.x + ah * 0.5f;  // NOTE: intentionally swapped (reference quirk)
      float pxc = acx + dxv * aw;
      float pyc = acy + dyv * ah;
      float pw = aw * expf(dwv);
      float ph = ah * expf(dhv);
      float b0 = pxc - pw * 0.5f, b1 = pyc - ph * 0.5f;
      float b2 = pxc + pw * 0.5f, b3 = pyc + ph * 0.5f;
      b0 = fminf(fmaxf(b0, 0.f), IMGF);
      b1 = fminf(fmaxf(b1, 0.f), IMGF);
      b2 = fminf(fmaxf(b2, 0.f), IMGF);
      b3 = fminf(fmaxf(b3, 0.f), IMGF);
      float hts = b2 - b0, wds = b3 - b1;
      bool valid = (hts > 0.f) && (wds > 0.f) && (score > OBJ_THRF);
      s[m] = valid ? score : NEGV;
      boxes[m] = make_float4(b0, b1, b2, b3);
    }
  }
}

// ---------------- sort phase 1: 8 blocks x 1024-elem bitonic runs ----------
__global__ __launch_bounds__(256) void k_sortA(const float* __restrict__ s,
                                               u64* __restrict__ keys) {
  __shared__ u64 lds[1024];
  const int tid = threadIdx.x;
  const int b = blockIdx.x;
  for (int v = tid; v < 1024; v += 256) {
    int i = b * 1024 + v;
    u64 p;
    if (i < MM) {
      u32 u = __float_as_uint(s[i]);
      u = u ^ (u32)(((int)u >> 31) | 0x80000000);
      p = ((u64)(~u) << 32) | (u32)i;
    } else {
      p = ~0ull;
    }
    lds[v] = p;
  }
  for (u32 kk = 2; kk <= 1024; kk <<= 1) {
    for (u32 j = kk >> 1; j > 0; j >>= 1) {
      __syncthreads();
#pragma unroll 2
      for (int t = tid; t < 512; t += 256) {
        int i = ((t & ~(j - 1)) << 1) | (t & (j - 1));
        int l = i | j;
        bool up = ((i & kk) == 0);
        u64 a = lds[i], c = lds[l];
        u64 mn = a < c ? a : c;
        u64 mx = a < c ? c : a;
        lds[i] = up ? mn : mx;
        lds[l] = up ? mx : mn;
      }
    }
  }
  __syncthreads();
  for (int v = tid; v < 1024; v += 256) keys[b * 1024 + v] = lds[v];
}

// ---------------- sort phase 2: merge-path rounds ----------------
__global__ __launch_bounds__(256) void k_merge(const u64* __restrict__ in,
                                               u64* __restrict__ outk, int L, int fin,
                                               const float* __restrict__ s,
                                               const float4* __restrict__ boxes,
                                               float* __restrict__ ssc,
                                               float4* __restrict__ sboxes) {
  const int i = blockIdx.x * 256 + threadIdx.x;  // 0..8191
  const int pair = i / (2 * L);
  const int r = i - pair * 2 * L;
  const u64* A = in + (size_t)pair * 2 * L;
  const u64* B = A + L;
  int lo = (r > L) ? (r - L) : 0;
  int hi = (r < L) ? r : L;
  while (lo < hi) {
    int mid = (lo + hi) >> 1;
    if (A[mid] < B[r - 1 - mid]) lo = mid + 1; else hi = mid;
  }
  int a = lo, bi = r - lo;
  u64 av = (a < L) ? A[a] : ~0ull;
  u64 bv = (bi < L) ? B[bi] : ~0ull;
  u64 o = (av < bv) ? av : bv;
  outk[i] = o;
  if (fin && i < MM) {
    int idx = (int)(u32)o;
    ssc[i] = s[idx];
    sboxes[i] = boxes[idx];
  }
}

// ---------------- zero-init nz bitmaps ----------------
__global__ __launch_bounds__(256) void k_zero(u64* __restrict__ nz) {
  int i = blockIdx.x * 256 + threadIdx.x;
  if (i < MM * 2) nz[i] = 0;
}

// ---------------- IOU suppression bit-matrix (transposed) ----------------
__global__ __launch_bounds__(256) void k_mask(const float4* __restrict__ sboxes,
                                              u64* __restrict__ mask_t,
                                              u64* __restrict__ nz) {
  __shared__ float4 rb_[64];
  const int rt = blockIdx.x;
  const int w = blockIdx.y * 4 + (threadIdx.x >> 6);
  const int lane = threadIdx.x & 63;
  if (threadIdx.x < 64) rb_[threadIdx.x] = sboxes[rt * 64 + threadIdx.x];
  __syncthreads();
  if (w < rt) return;
  float4 c = sboxes[w * 64 + lane];
  float areaC = (c.z - c.x) * (c.w - c.y);
  u64 myw = 0;
  for (int r = 0; r < 64; ++r) {
    float4 b = rb_[r];
    float iw = fmaxf(fminf(b.z, c.z) - fmaxf(b.x, c.x), 0.f);
    float ih = fmaxf(fminf(b.w, c.w) - fmaxf(b.y, c.y), 0.f);
    float inter = iw * ih;
    float areaB = (b.z - b.x) * (b.w - b.y);
    float un = fmaxf(areaB + areaC - inter, 1e-9f);
    bool bit = (inter / un) > IOU_THRF;
    u64 bal = __ballot(bit);
    if (lane == r) myw = bal;
  }
  mask_t[(size_t)w * MM + rt * 64 + lane] = myw;
  if (myw) atomicOr(&nz[(rt * 64 + lane) * 2 + (w >> 6)], 1ull << (w & 63));
}

// ---------------- serial NMS scan + output ----------------
__global__ __launch_bounds__(256) void k_scan(const u64* __restrict__ mask_t,
                                              const u64* __restrict__ nz,
                                              const float* __restrict__ ssc,
                                              const float4* __restrict__ sboxes,
                                              float* __restrict__ out) {
  __shared__ u64 remv[NW];
  __shared__ u64 keepw[NW];
  __shared__ int blist[64];
  __shared__ int nkS;
  __shared__ int kcntS;
  __shared__ int pref[NW];
  const int tid = threadIdx.x;
  if (tid < NW) { remv[tid] = 0; keepw[tid] = 0; }
  if (tid == 0) kcntS = 0;
  __syncthreads();

  for (int c = 0; c < NW; ++c) {
    if (tid < 64) {
      const int lane = tid;
      u64 dg = mask_t[(size_t)c * MM + c * 64 + lane];
      float sv = ssc[c * 64 + lane];
      u64 vb = __ballot(sv > OBJ_THRF);
      u64 w0 = remv[c];
      u64 cand = vb & ~w0;
      u64 above = (lane < 63) ? ~((2ull << lane) - 1ull) : 0ull;
      bool inC = ((cand >> lane) & 1ull) != 0;
      u64 conf = __ballot(inC && ((dg & above & cand) != 0ull));
      u64 kb;
      if (conf == 0ull) {
        kb = cand;
      } else {
        u64 w = w0;
        kb = 0;
        u64 rem = cand;
        while (rem) {
          int b = __ffsll(rem) - 1;
          kb |= (1ull << b);
          w |= shfl64(dg, b);
          rem = vb & ~w;
        }
      }
      int below = __popcll(kb & ((1ull << lane) - 1ull));
      if ((kb >> lane) & 1ull) blist[below] = lane;
      if (lane == 0) {
        keepw[c] = kb;
        nkS = __popcll(kb);
        kcntS += __popcll(kb);
      }
    }
    __syncthreads();
    int nk = nkS;
    if (tid < nk) {
      int row = c * 64 + blist[tid];
      u64 nz0 = nz[row * 2], nz1 = nz[row * 2 + 1];
      if (c < 64) {
        nz0 &= (c < 63) ? ~((2ull << c) - 1ull) : 0ull;
      } else {
        nz0 = 0;
        int cc = c - 64;
        nz1 &= ~((2ull << cc) - 1ull);
      }
      while (nz0) {
        int wv = __ffsll(nz0) - 1; nz0 &= nz0 - 1;
        atomicOr(&remv[wv], mask_t[(size_t)wv * MM + row]);
      }
      while (nz1) {
        int wv = __ffsll(nz1) - 1; nz1 &= nz1 - 1;
        atomicOr(&remv[wv + 64], mask_t[(size_t)(wv + 64) * MM + row]);
      }
    }
    __syncthreads();
    if (kcntS >= TOPK) break;
  }

  if (tid == 0) {
    int run = 0;
    for (int cc = 0; cc < NW; ++cc) { pref[cc] = run; run += __popcll(keepw[cc]); }
  }
  __syncthreads();
  for (int e = tid; e < TOPK * 5; e += 256) out[e] = (e < TOPK) ? -1.0f : 0.0f;
  __syncthreads();
  float4* ob = (float4*)(out + TOPK);
  for (int i = tid; i < MM; i += 256) {
    int cc = i >> 6, b = i & 63;
    u64 kb = keepw[cc];
    if ((kb >> b) & 1ull) {
      int rank = pref[cc] + __popcll(kb & ((1ull << b) - 1ull));
      if (rank < TOPK) {
        out[rank] = ssc[i];
        ob[rank] = sboxes[i];
      }
    }
  }
}

extern "C" void kernel_launch(void* const* d_in, const int* in_sizes, int n_in,
                              void* d_out, int out_size, void* d_ws, size_t ws_size,
                              hipStream_t stream) {
  const float* x  = (const float*)d_in[0];
  const float* cw = (const float*)d_in[1];
  const float* cb = (const float*)d_in[2];
  const float* dw = (const float*)d_in[3];
  const float* db = (const float*)d_in[4];
  const float* rw = (const float*)d_in[5];
  const float* rb = (const float*)d_in[6];
  const float* an = (const float*)d_in[7];
  char* ws = (char*)d_ws;
  // Time-phased aliasing of [0 .. 18.9MB):
  //   phase 1 (k_wt,k_conv,k_decode): part
  //   phase 2 (k_zero..k_merge): keysA/B at [0..128KB), nz at 5,971,968
  //   phase 3 (k_mask,k_scan): mask at [0..5,971,968)
  float*  part   = (float*)(ws);                 // 18,874,368 B (KSPLIT*256*NPX*4)
  u64*    keysA  = (u64*)(ws);                   // 65,536 B
  u64*    keysB  = (u64*)(ws + 65536);           // 65,536 B
  u64*    mask   = (u64*)(ws);                   // 5,971,968 B
  u64*    nz     = (u64*)(ws + 5971968);         // 110,592 B
  float*  wt     = (float*)(ws + 18874368);      // 2,359,296 B
  float*  s      = (float*)(ws + 21233664);      // 27,648 B
  float4* boxes  = (float4*)(ws + 21261312);     // 110,592 B
  float*  ssc    = (float*)(ws + 21371904);      // 27,648 B
  float4* sboxes = (float4*)(ws + 21399552);     // 110,592 B -> total 21,510,144 B
  float* out = (float*)d_out;

  hipLaunchKernelGGL(k_wt, dim3(36, 4), dim3(256), 0, stream, cw, wt);
  hipLaunchKernelGGL(k_conv, dim3(9, 16, KSPLIT), dim3(256), 0, stream, x, wt, part);
  hipLaunchKernelGGL(k_decode, dim3(36), dim3(256), 0, stream, part, cb, dw, db, rw, rb, an, s, boxes);
  hipLaunchKernelGGL(k_zero, dim3(54), dim3(256), 0, stream, nz);
  hipLaunchKernelGGL(k_sortA, dim3(8), dim3(256), 0, stream, s, keysA);
  hipLaunchKernelGGL(k_merge, dim3(32), dim3(256), 0, stream, keysA, keysB, 1024, 0, s, boxes, ssc, sboxes);
  hipLaunchKernelGGL(k_merge, dim3(32), dim3(256), 0, stream, keysB, keysA, 2048, 0, s, boxes, ssc, sboxes);
  hipLaunchKernelGGL(k_merge, dim3(32), dim3(256), 0, stream, keysA, keysB, 4096, 1, s, boxes, ssc, sboxes);
  hipLaunchKernelGGL(k_mask, dim3(108, 27), dim3(256), 0, stream, sboxes, mask, nz);
  hipLaunchKernelGGL(k_scan, dim3(1), dim3(256), 0, stream, mask, nz, ssc, sboxes, out);
}